// Round 11
// baseline (322.131 us; speedup 1.0000x reference)
//
#include <hip/hip_runtime.h>
#include <hip/hip_bf16.h>
#include <math.h>

#define BSZ 4
#define NSEQ 2048
#define CDIM 1024
#define NH 16
#define DH 64
#define KC 64
#define KMAX_STRIDE 32   // one kmax slot per 128B cacheline

typedef _Float16 half8_t __attribute__((ext_vector_type(8)));
typedef _Float16 half4_t __attribute__((ext_vector_type(4)));
typedef __fp16 pk2_t __attribute__((ext_vector_type(2)));   // cvt_pkrtz/fdot2 type
typedef __fp16 pk4_t __attribute__((ext_vector_type(4)));
typedef float floatx4 __attribute__((ext_vector_type(4)));

#define GLOBAL_AS(p) ((const __attribute__((address_space(1))) void*)(p))
#define LDS_AS(p)    ((__attribute__((address_space(3))) void*)(p))

// ---------------------------------------------------------------------------
// Fused prep: one dispatch covering
//   [0,4096)      cast x fp32->fp16
//   [4096,4864)   transpose+cast Wqkv -> Wt[3072][1024]
//   [4864,5120)   transpose+cast Wproj -> Wpt[1024][1024]
//   [5120,5376)   RoPE (cos,sin) table + kmax zero-init
// ---------------------------------------------------------------------------
__global__ __launch_bounds__(256) void prep_kernel(
    const float* __restrict__ x, const float* __restrict__ Wqkv,
    const float* __restrict__ Wproj, _Float16* __restrict__ xh,
    _Float16* __restrict__ Wt, _Float16* __restrict__ Wpt,
    float2* __restrict__ ropet, unsigned* __restrict__ kmaxu) {
  __shared__ float Ls[64][65];
  const int t = threadIdx.x;
  const int bid = blockIdx.x;

  if (bid < 4096) {                      // ---- cast x ----
    const size_t i = ((size_t)bid * 256 + t) * 8;
    float4 a = *(const float4*)(x + i);
    float4 b = *(const float4*)(x + i + 4);
    half8_t h;
    h[0] = (_Float16)a.x; h[1] = (_Float16)a.y; h[2] = (_Float16)a.z; h[3] = (_Float16)a.w;
    h[4] = (_Float16)b.x; h[5] = (_Float16)b.y; h[6] = (_Float16)b.z; h[7] = (_Float16)b.w;
    *(half8_t*)(xh + i) = h;
    return;
  }
  if (bid >= 5120) {                     // ---- rope table + kmax init ----
    const int idx = (bid - 5120) * 256 + t;   // 65536 entries
    const int n = idx >> 5, f = idx & 31;
    const float invf = expf(-9.210340371976184f * ((float)f * (1.0f / 32.0f)));
    float s, c;
    sincosf((float)n * invf, &s, &c);
    ropet[idx] = make_float2(c, s);
    if (bid == 5120)
      for (int i2 = t; i2 < 64 * KMAX_STRIDE; i2 += 256) kmaxu[i2] = 0u;
    return;
  }
  // ---- transpose+cast ----
  const float* src;
  _Float16* dst;
  int R, C, bx, by;
  if (bid < 4864) {
    src = Wqkv; dst = Wt; R = 1024; C = 3072;
    bx = (bid - 4096) % 48; by = (bid - 4096) / 48;
  } else {
    src = Wproj; dst = Wpt; R = 1024; C = 1024;
    bx = (bid - 4864) % 16; by = (bid - 4864) / 16;
  }
  const int r0 = by * 64, c0 = bx * 64;
  {
    const int lr = t >> 2, lcg = (t & 3) * 16;
    const float* s = src + (size_t)(r0 + lr) * C + c0 + lcg;
#pragma unroll
    for (int u = 0; u < 4; ++u)
      *(float4*)&Ls[lr][lcg + 4 * u] = *(const float4*)(s + 4 * u);
  }
  __syncthreads();
  const int c = t >> 2, rg = (t & 3) * 16;
  half8_t h0, h1;
#pragma unroll
  for (int u = 0; u < 8; ++u) h0[u] = (_Float16)Ls[rg + u][c];
#pragma unroll
  for (int u = 0; u < 8; ++u) h1[u] = (_Float16)Ls[rg + 8 + u][c];
  _Float16* d = dst + (size_t)(c0 + c) * R + r0 + rg;
  *(half8_t*)d = h0;
  *(half8_t*)(d + 8) = h1;
}

// ---------------------------------------------------------------------------
// Kernel 1: QKV GEMM (fp16 MFMA) + bias + RoPE epilogue (table-based).
// R11: q-row norms / k-row-norm max fused into the epilogue — each head's 64
// dims live in one wave (nt*16+m); 16-lane shfl_xor m-reduce gives row sums
// of the fp16-ROUNDED stored values (bit-identical to the old qk_norms).
// Kills the separate qk_norms pass (64MB re-read + one launch).
// ---------------------------------------------------------------------------
__global__ __launch_bounds__(256) void qkv_gemm_kernel(
    const _Float16* __restrict__ xh, const _Float16* __restrict__ Wt,
    const float* __restrict__ bias, const float2* __restrict__ rope,
    _Float16* __restrict__ Qh, _Float16* __restrict__ Kh,
    _Float16* __restrict__ Vh, float* __restrict__ qn,
    unsigned* __restrict__ kmaxu) {
  __shared__ _Float16 As[128 * 64];
  __shared__ _Float16 Bs[128 * 64];
  const int tid = threadIdx.x;
  const int lane = tid & 63, w = tid >> 6;
  const int m = lane & 15, quad = lane >> 4;
  const int wr = (w >> 1) * 64, wc = (w & 1) * 64;
  const int m0 = blockIdx.y * 128;
  const int N0 = blockIdx.x * 128;
  const int sr = lane >> 3, sc = (lane & 7) * 8;

  floatx4 acc[4][4];
#pragma unroll
  for (int i = 0; i < 4; ++i)
#pragma unroll
    for (int j = 0; j < 4; ++j) acc[i][j] = (floatx4){0.f, 0.f, 0.f, 0.f};

  for (int k0 = 0; k0 < CDIM; k0 += 64) {
    __syncthreads();
#pragma unroll
    for (int i = 0; i < 4; ++i) {
      const int row = (w * 4 + i) * 8 + sr;
      __builtin_amdgcn_global_load_lds(
          GLOBAL_AS(xh + (size_t)(m0 + row) * CDIM + k0 + sc),
          LDS_AS(As + (w * 4 + i) * 512), 16, 0, 0);
      __builtin_amdgcn_global_load_lds(
          GLOBAL_AS(Wt + (size_t)(N0 + row) * CDIM + k0 + sc),
          LDS_AS(Bs + (w * 4 + i) * 512), 16, 0, 0);
    }
    __syncthreads();
#pragma unroll
    for (int ks = 0; ks < 2; ++ks) {
      half8_t af[4], bf[4];
#pragma unroll
      for (int mt = 0; mt < 4; ++mt)
        af[mt] = *(half8_t*)(As + (wr + mt * 16 + m) * 64 + ks * 32 + quad * 8);
#pragma unroll
      for (int nt = 0; nt < 4; ++nt)
        bf[nt] = *(half8_t*)(Bs + (wc + nt * 16 + m) * 64 + ks * 32 + quad * 8);
#pragma unroll
      for (int mt = 0; mt < 4; ++mt)
#pragma unroll
        for (int nt = 0; nt < 4; ++nt)
          acc[mt][nt] = __builtin_amdgcn_mfma_f32_16x16x32_f16(
              af[mt], bf[nt], acc[mt][nt], 0, 0, 0);
    }
  }

  const int F0 = N0 + wc;
  const int which = F0 >> 10;
  const int head = (F0 & 1023) >> 6;
  float bv[4];
#pragma unroll
  for (int nt = 0; nt < 4; ++nt) bv[nt] = bias[F0 + nt * 16 + m];

  if (which == 2) {
#pragma unroll
    for (int mt = 0; mt < 4; ++mt)
#pragma unroll
      for (int reg = 0; reg < 4; ++reg) {
        const int gm = m0 + wr + mt * 16 + 4 * quad + reg;
        const int b = gm >> 11, n = gm & 2047;
        const size_t vbase = ((size_t)(b * NH + head) * DH) * NSEQ + n;
#pragma unroll
        for (int nt = 0; nt < 4; ++nt)
          Vh[vbase + (size_t)(nt * 16 + m) * NSEQ] =
              (_Float16)(acc[mt][nt][reg] + bv[nt]);
      }
  } else {
    _Float16* dst = which ? Kh : Qh;
    const float qs = which ? 1.0f : 0.125f * 1.4426950408889634f;
    float ssum[4][4];
#pragma unroll
    for (int mt = 0; mt < 4; ++mt)
#pragma unroll
      for (int reg = 0; reg < 4; ++reg) ssum[mt][reg] = 0.f;
#pragma unroll
    for (int mt = 0; mt < 4; ++mt)
#pragma unroll
      for (int reg = 0; reg < 4; ++reg) {
        const int gm = m0 + wr + mt * 16 + 4 * quad + reg;
        const int b = gm >> 11, n = gm & 2047;
        const float2 csA = rope[n * 32 + m];       // freq index m
        const float2 csB = rope[n * 32 + 16 + m];  // freq index 16+m
        const size_t obase = ((size_t)(b * NH + head) * NSEQ + n) * DH;
#pragma unroll
        for (int nt = 0; nt < 4; ++nt) {
          const float val = acc[mt][nt][reg] + bv[nt];
          const float rot = (nt < 2) ? -(acc[mt][nt + 2][reg] + bv[nt + 2])
                                     :  (acc[mt][nt - 2][reg] + bv[nt - 2]);
          const float sv = (nt & 1) ? csB.y : csA.y;
          const float cv = (nt & 1) ? csB.x : csA.x;
          const _Float16 h16 = (_Float16)((val * cv + rot * sv) * qs);
          dst[obase + nt * 16 + m] = h16;
          const float vv = (float)h16;
          ssum[mt][reg] += vv * vv;
        }
      }
    // row sums: reduce over the 16 m-lanes (dims nt*16+m; nt already summed)
#pragma unroll
    for (int mt = 0; mt < 4; ++mt)
#pragma unroll
      for (int reg = 0; reg < 4; ++reg) {
        float s = ssum[mt][reg];
        s += __shfl_xor(s, 1, 64);
        s += __shfl_xor(s, 2, 64);
        s += __shfl_xor(s, 4, 64);
        s += __shfl_xor(s, 8, 64);
        ssum[mt][reg] = s;
      }
    if (which == 0) {
      if (m == 0) {
#pragma unroll
        for (int mt = 0; mt < 4; ++mt)
#pragma unroll
          for (int reg = 0; reg < 4; ++reg) {
            const int gm = m0 + wr + mt * 16 + 4 * quad + reg;
            const int b = gm >> 11, n = gm & 2047;
            qn[(size_t)(b * NH + head) * NSEQ + n] = sqrtf(ssum[mt][reg]);
          }
      }
    } else {
      float mx = 0.f;
#pragma unroll
      for (int mt = 0; mt < 4; ++mt)
#pragma unroll
        for (int reg = 0; reg < 4; ++reg) mx = fmaxf(mx, ssum[mt][reg]);
      mx = fmaxf(mx, __shfl_xor(mx, 16, 64));
      mx = fmaxf(mx, __shfl_xor(mx, 32, 64));
      if (lane == 0) {
        const int b = m0 >> 11;   // 128-row block never straddles a batch
        atomicMax(&kmaxu[(b * NH + head) * KMAX_STRIDE],
                  __float_as_uint(sqrtf(mx)));
      }
    }
  }
}

// ---------------------------------------------------------------------------
// Kernel 2: flash attention (R10 structure, unchanged: 512 thr / 8 waves,
// 16 q-rows per wave, VGPR<=64 -> 8 waves/SIMD, XCD-aware decode).
// ---------------------------------------------------------------------------
__global__ __launch_bounds__(512, 8) void attn_kernel(
    const _Float16* __restrict__ Qh, const _Float16* __restrict__ Kh,
    const _Float16* __restrict__ Vh, const float* __restrict__ qn,
    const unsigned* __restrict__ kmaxu, _Float16* __restrict__ AO) {
  __shared__ _Float16 smem[17408];   // 34816 B: Ks[64][72]+Vt[64][72] stage
  float* Os = (float*)smem;          // epilogue reuse: float[128][68]
  _Float16* Ks = smem;               // [64][72]
  _Float16* Vt = smem + 4608;        // [64][72]

  const int tid = threadIdx.x;
  const int lane = tid & 63;
  const int w = tid >> 6;            // 0..7
  const int m = lane & 15;
  const int quad = lane >> 4;

  // XCD-aware decode: slot = id%8 (XCD), k = id/8; bh = slot + 8*(k/16)
  const int bid = blockIdx.x;
  const int slot = bid & 7, kk = bid >> 3;
  const int bh = slot + 8 * (kk >> 4);
  const int q0 = (kk & 15) * 128;

  const _Float16* Qb = Qh + (size_t)bh * NSEQ * DH;
  const _Float16* Kb = Kh + (size_t)bh * NSEQ * DH;
  const _Float16* Vb = Vh + (size_t)bh * DH * NSEQ;

  const int rA = q0 + w * 16 + m;    // wave w owns rows q0+w*16 .. +16
  half8_t qfA0 = *(const half8_t*)(Qb + (size_t)rA * DH + quad * 8);
  half8_t qfA1 = *(const half8_t*)(Qb + (size_t)rA * DH + 32 + quad * 8);

  const float kmx = __uint_as_float(kmaxu[bh * KMAX_STRIDE]);
  const float mA = qn[(size_t)bh * NSEQ + rA] * kmx;

  // staging: 512 threads, each moves 1 K half8 + 1 V half8 per chunk
  const int skey = tid >> 3, sdg = (tid & 7) * 8;
  const _Float16* ksrc = Kb + (size_t)skey * DH + sdg;
  const _Float16* vsrc = Vb + (size_t)skey * NSEQ + sdg;
  const int koff = skey * 72 + sdg;

  float lA = 0.f;
  floatx4 OA[4];
#pragma unroll
  for (int nb = 0; nb < 4; ++nb) OA[nb] = (floatx4){0.f, 0.f, 0.f, 0.f};
  const pk2_t one2 = {(__fp16)1.f, (__fp16)1.f};

  const int NCK = NSEQ / KC;  // 32
  for (int ck = 0; ck < NCK; ++ck) {
    half8_t k8 = *(const half8_t*)ksrc;  ksrc += KC * DH;
    half8_t v8 = *(const half8_t*)vsrc;  vsrc += KC;
    __syncthreads();                 // prev compute done, LDS free
    *(half8_t*)(Ks + koff) = k8;
    *(half8_t*)(Vt + koff) = v8;
    __syncthreads();                 // stage visible

#pragma unroll
    for (int kt = 0; kt < 4; ++kt) {
      half8_t kf0 = *(half8_t*)(Ks + (kt * 16 + m) * 72 + quad * 8);
      half8_t kf1 = *(half8_t*)(Ks + (kt * 16 + m) * 72 + 32 + quad * 8);
      __builtin_amdgcn_s_setprio(1);
      floatx4 a = (floatx4){-mA, -mA, -mA, -mA};
      a = __builtin_amdgcn_mfma_f32_16x16x32_f16(kf0, qfA0, a, 0, 0, 0);
      a = __builtin_amdgcn_mfma_f32_16x16x32_f16(kf1, qfA1, a, 0, 0, 0);
      __builtin_amdgcn_s_setprio(0);

      pk2_t a01 = __builtin_amdgcn_cvt_pkrtz(__builtin_exp2f(a[0]),
                                             __builtin_exp2f(a[1]));
      pk2_t a23 = __builtin_amdgcn_cvt_pkrtz(__builtin_exp2f(a[2]),
                                             __builtin_exp2f(a[3]));
      lA = __builtin_amdgcn_fdot2(a01, one2, lA, false);
      lA = __builtin_amdgcn_fdot2(a23, one2, lA, false);
      half4_t phA = __builtin_bit_cast(
          half4_t, (pk4_t)__builtin_shufflevector(a01, a23, 0, 1, 2, 3));

      __builtin_amdgcn_s_setprio(1);
#pragma unroll
      for (int nb = 0; nb < 4; ++nb) {
        half4_t vf = *(half4_t*)(Vt + (nb * 16 + m) * 72 + kt * 16 + quad * 4);
        OA[nb] = __builtin_amdgcn_mfma_f32_16x16x16f16(phA, vf, OA[nb], 0, 0, 0);
      }
      __builtin_amdgcn_s_setprio(0);
    }
  }

  // row-sum across quads (lanes differing in bits 4,5)
  lA += __shfl_xor(lA, 16, 64); lA += __shfl_xor(lA, 32, 64);
  float lA4[4];
#pragma unroll
  for (int r = 0; r < 4; ++r) lA4[r] = __shfl(lA, 4 * quad + r, 64);

  const int b = bh >> 4, h = bh & 15;
  const int ql = tid >> 2, dgo = (tid & 3) * 16;   // ql 0..127
  const int gq = q0 + ql;
  _Float16* dst = AO + ((size_t)(b * NSEQ + gq)) * CDIM + h * DH + dgo;

  __syncthreads();   // all compute reads of Ks/Vt done before Os overwrite
#pragma unroll
  for (int nb = 0; nb < 4; ++nb)
#pragma unroll
    for (int r = 0; r < 4; ++r)
      Os[(w * 16 + 4 * quad + r) * 68 + nb * 16 + m] = OA[nb][r] * (1.0f / lA4[r]);
  __syncthreads();
#pragma unroll
  for (int u = 0; u < 2; ++u) {
    half8_t o;
#pragma unroll
    for (int v = 0; v < 8; ++v) o[v] = (_Float16)Os[ql * 68 + dgo + u * 8 + v];
    *(half8_t*)(dst + u * 8) = o;
  }
}

// ---------------------------------------------------------------------------
// Kernel 3: proj GEMM (fp16 MFMA) + bias, fp32 out (unchanged R3).
// ---------------------------------------------------------------------------
__global__ __launch_bounds__(256) void proj_gemm_kernel(
    const _Float16* __restrict__ Ah, const _Float16* __restrict__ Wt,
    const float* __restrict__ bias, float* __restrict__ out) {
  __shared__ _Float16 As[128 * 64];
  __shared__ _Float16 Bs[128 * 64];
  const int tid = threadIdx.x;
  const int lane = tid & 63, w = tid >> 6;
  const int m = lane & 15, quad = lane >> 4;
  const int wr = (w >> 1) * 64, wc = (w & 1) * 64;
  const int m0 = blockIdx.y * 128;
  const int N0 = blockIdx.x * 128;
  const int sr = lane >> 3, sc = (lane & 7) * 8;

  floatx4 acc[4][4];
#pragma unroll
  for (int i = 0; i < 4; ++i)
#pragma unroll
    for (int j = 0; j < 4; ++j) acc[i][j] = (floatx4){0.f, 0.f, 0.f, 0.f};

  for (int k0 = 0; k0 < CDIM; k0 += 64) {
    __syncthreads();
#pragma unroll
    for (int i = 0; i < 4; ++i) {
      const int row = (w * 4 + i) * 8 + sr;
      __builtin_amdgcn_global_load_lds(
          GLOBAL_AS(Ah + (size_t)(m0 + row) * CDIM + k0 + sc),
          LDS_AS(As + (w * 4 + i) * 512), 16, 0, 0);
      __builtin_amdgcn_global_load_lds(
          GLOBAL_AS(Wt + (size_t)(N0 + row) * CDIM + k0 + sc),
          LDS_AS(Bs + (w * 4 + i) * 512), 16, 0, 0);
    }
    __syncthreads();
#pragma unroll
    for (int ks = 0; ks < 2; ++ks) {
      half8_t af[4], bf[4];
#pragma unroll
      for (int mt = 0; mt < 4; ++mt)
        af[mt] = *(half8_t*)(As + (wr + mt * 16 + m) * 64 + ks * 32 + quad * 8);
#pragma unroll
      for (int nt = 0; nt < 4; ++nt)
        bf[nt] = *(half8_t*)(Bs + (wc + nt * 16 + m) * 64 + ks * 32 + quad * 8);
#pragma unroll
      for (int mt = 0; mt < 4; ++mt)
#pragma unroll
        for (int nt = 0; nt < 4; ++nt)
          acc[mt][nt] = __builtin_amdgcn_mfma_f32_16x16x32_f16(
              af[mt], bf[nt], acc[mt][nt], 0, 0, 0);
    }
  }

  const int F0 = N0 + wc;
  float bv[4];
#pragma unroll
  for (int nt = 0; nt < 4; ++nt) bv[nt] = bias[F0 + nt * 16 + m];
#pragma unroll
  for (int mt = 0; mt < 4; ++mt)
#pragma unroll
    for (int reg = 0; reg < 4; ++reg) {
      const int gm = m0 + wr + mt * 16 + 4 * quad + reg;
#pragma unroll
      for (int nt = 0; nt < 4; ++nt)
        out[(size_t)gm * CDIM + F0 + nt * 16 + m] = acc[mt][nt][reg] + bv[nt];
    }
}

// ---------------------------------------------------------------------------
extern "C" void kernel_launch(void* const* d_in, const int* in_sizes, int n_in,
                              void* d_out, int out_size, void* d_ws, size_t ws_size,
                              hipStream_t stream) {
  const float* x     = (const float*)d_in[0];
  const float* Wqkv  = (const float*)d_in[1];
  const float* bqkv  = (const float*)d_in[2];
  const float* Wproj = (const float*)d_in[3];
  const float* bproj = (const float*)d_in[4];
  float* out = (float*)d_out;

  const size_t per = (size_t)BSZ * NH * NSEQ * DH;  // 8,388,608
  _Float16* xh  = (_Float16*)d_ws;
  _Float16* Wt  = xh + per;                 // [3072][1024]
  _Float16* Wpt = Wt + (size_t)3072 * 1024; // [1024][1024]
  _Float16* Qh  = Wpt + (size_t)1024 * 1024;
  _Float16* Kh  = Qh + per;
  _Float16* Vh  = Kh + per;
  _Float16* AOh = Vh + per;
  float*    qnp = (float*)(AOh + per);      // [64*2048] q-row norms
  unsigned* kmx = (unsigned*)(qnp + (size_t)64 * NSEQ);  // [64*KMAX_STRIDE]
  float2*   ropet = (float2*)(kmx + 64 * KMAX_STRIDE);   // [2048*32] (cos,sin)

  prep_kernel<<<5376, 256, 0, stream>>>(x, Wqkv, Wproj, xh, Wt, Wpt, ropet, kmx);
  qkv_gemm_kernel<<<dim3(24, 64), 256, 0, stream>>>(xh, Wt, bqkv, ropet,
                                                    Qh, Kh, Vh, qnp, kmx);
  attn_kernel<<<1024, 512, 0, stream>>>(Qh, Kh, Vh, qnp, kmx, AOh);
  proj_gemm_kernel<<<dim3(8, 64), 256, 0, stream>>>(AOh, Wpt, bproj, out);
}

// Round 12
// 310.606 us; speedup vs baseline: 1.0371x; 1.0371x over previous
//
#include <hip/hip_runtime.h>
#include <hip/hip_bf16.h>
#include <math.h>

#define BSZ 4
#define NSEQ 2048
#define CDIM 1024
#define NH 16
#define DH 64
#define KC 64
#define KMAX_STRIDE 32   // one kmax slot per 128B cacheline

typedef _Float16 half8_t __attribute__((ext_vector_type(8)));
typedef _Float16 half4_t __attribute__((ext_vector_type(4)));
typedef __fp16 pk2_t __attribute__((ext_vector_type(2)));   // cvt_pkrtz/fdot2 type
typedef __fp16 pk4_t __attribute__((ext_vector_type(4)));
typedef float floatx4 __attribute__((ext_vector_type(4)));

#define GLOBAL_AS(p) ((const __attribute__((address_space(1))) void*)(p))
#define LDS_AS(p)    ((__attribute__((address_space(3))) void*)(p))

// ---------------------------------------------------------------------------
// Fused prep: one dispatch covering
//   [0,4096)      cast x fp32->fp16
//   [4096,4864)   transpose+cast Wqkv -> Wt[3072][1024]
//   [4864,5120)   transpose+cast Wproj -> Wpt[1024][1024]
//   [5120,5376)   RoPE (cos,sin) table + kmax zero-init
// ---------------------------------------------------------------------------
__global__ __launch_bounds__(256) void prep_kernel(
    const float* __restrict__ x, const float* __restrict__ Wqkv,
    const float* __restrict__ Wproj, _Float16* __restrict__ xh,
    _Float16* __restrict__ Wt, _Float16* __restrict__ Wpt,
    float2* __restrict__ ropet, unsigned* __restrict__ kmaxu) {
  __shared__ float Ls[64][65];
  const int t = threadIdx.x;
  const int bid = blockIdx.x;

  if (bid < 4096) {                      // ---- cast x ----
    const size_t i = ((size_t)bid * 256 + t) * 8;
    float4 a = *(const float4*)(x + i);
    float4 b = *(const float4*)(x + i + 4);
    half8_t h;
    h[0] = (_Float16)a.x; h[1] = (_Float16)a.y; h[2] = (_Float16)a.z; h[3] = (_Float16)a.w;
    h[4] = (_Float16)b.x; h[5] = (_Float16)b.y; h[6] = (_Float16)b.z; h[7] = (_Float16)b.w;
    *(half8_t*)(xh + i) = h;
    return;
  }
  if (bid >= 5120) {                     // ---- rope table + kmax init ----
    const int idx = (bid - 5120) * 256 + t;   // 65536 entries
    const int n = idx >> 5, f = idx & 31;
    const float invf = expf(-9.210340371976184f * ((float)f * (1.0f / 32.0f)));
    float s, c;
    sincosf((float)n * invf, &s, &c);
    ropet[idx] = make_float2(c, s);
    if (bid == 5120)
      for (int i2 = t; i2 < 64 * KMAX_STRIDE; i2 += 256) kmaxu[i2] = 0u;
    return;
  }
  // ---- transpose+cast ----
  const float* src;
  _Float16* dst;
  int R, C, bx, by;
  if (bid < 4864) {
    src = Wqkv; dst = Wt; R = 1024; C = 3072;
    bx = (bid - 4096) % 48; by = (bid - 4096) / 48;
  } else {
    src = Wproj; dst = Wpt; R = 1024; C = 1024;
    bx = (bid - 4864) % 16; by = (bid - 4864) / 16;
  }
  const int r0 = by * 64, c0 = bx * 64;
  {
    const int lr = t >> 2, lcg = (t & 3) * 16;
    const float* s = src + (size_t)(r0 + lr) * C + c0 + lcg;
#pragma unroll
    for (int u = 0; u < 4; ++u)
      *(float4*)&Ls[lr][lcg + 4 * u] = *(const float4*)(s + 4 * u);
  }
  __syncthreads();
  const int c = t >> 2, rg = (t & 3) * 16;
  half8_t h0, h1;
#pragma unroll
  for (int u = 0; u < 8; ++u) h0[u] = (_Float16)Ls[rg + u][c];
#pragma unroll
  for (int u = 0; u < 8; ++u) h1[u] = (_Float16)Ls[rg + 8 + u][c];
  _Float16* d = dst + (size_t)(c0 + c) * R + r0 + rg;
  *(half8_t*)d = h0;
  *(half8_t*)(d + 8) = h1;
}

// ---------------------------------------------------------------------------
// Kernel 1: QKV GEMM (fp16 MFMA) + bias + RoPE epilogue (table-based) +
// fused q/k norms (R11). R12: V epilogue routed through LDS — the old path
// stored 2B scalars at 4KB stride (16 cachelines/instr, 8B useful each,
// ~16x write amplification on 16MB). Now: per head, waves ds_write_b64
// their fragments into Vl[64][132], then all 256 threads store coalesced
// half8 (256B fully-written segments per d-row).
// ---------------------------------------------------------------------------
__global__ __launch_bounds__(256) void qkv_gemm_kernel(
    const _Float16* __restrict__ xh, const _Float16* __restrict__ Wt,
    const float* __restrict__ bias, const float2* __restrict__ rope,
    _Float16* __restrict__ Qh, _Float16* __restrict__ Kh,
    _Float16* __restrict__ Vh, float* __restrict__ qn,
    unsigned* __restrict__ kmaxu) {
  __shared__ _Float16 smem[16384];   // As[8192] | Bs[8192]; V-epi reuses as Vl
  _Float16* As = smem;
  _Float16* Bs = smem + 8192;
  const int tid = threadIdx.x;
  const int lane = tid & 63, w = tid >> 6;
  const int m = lane & 15, quad = lane >> 4;
  const int wr = (w >> 1) * 64, wc = (w & 1) * 64;
  const int m0 = blockIdx.y * 128;
  const int N0 = blockIdx.x * 128;
  const int sr = lane >> 3, sc = (lane & 7) * 8;

  floatx4 acc[4][4];
#pragma unroll
  for (int i = 0; i < 4; ++i)
#pragma unroll
    for (int j = 0; j < 4; ++j) acc[i][j] = (floatx4){0.f, 0.f, 0.f, 0.f};

  for (int k0 = 0; k0 < CDIM; k0 += 64) {
    __syncthreads();
#pragma unroll
    for (int i = 0; i < 4; ++i) {
      const int row = (w * 4 + i) * 8 + sr;
      __builtin_amdgcn_global_load_lds(
          GLOBAL_AS(xh + (size_t)(m0 + row) * CDIM + k0 + sc),
          LDS_AS(As + (w * 4 + i) * 512), 16, 0, 0);
      __builtin_amdgcn_global_load_lds(
          GLOBAL_AS(Wt + (size_t)(N0 + row) * CDIM + k0 + sc),
          LDS_AS(Bs + (w * 4 + i) * 512), 16, 0, 0);
    }
    __syncthreads();
#pragma unroll
    for (int ks = 0; ks < 2; ++ks) {
      half8_t af[4], bf[4];
#pragma unroll
      for (int mt = 0; mt < 4; ++mt)
        af[mt] = *(half8_t*)(As + (wr + mt * 16 + m) * 64 + ks * 32 + quad * 8);
#pragma unroll
      for (int nt = 0; nt < 4; ++nt)
        bf[nt] = *(half8_t*)(Bs + (wc + nt * 16 + m) * 64 + ks * 32 + quad * 8);
#pragma unroll
      for (int mt = 0; mt < 4; ++mt)
#pragma unroll
        for (int nt = 0; nt < 4; ++nt)
          acc[mt][nt] = __builtin_amdgcn_mfma_f32_16x16x32_f16(
              af[mt], bf[nt], acc[mt][nt], 0, 0, 0);
    }
  }

  const int F0 = N0 + wc;
  const int which = F0 >> 10;          // block-uniform (1024 % 128 == 0)
  const int head = (F0 & 1023) >> 6;
  float bv[4];
#pragma unroll
  for (int nt = 0; nt < 4; ++nt) bv[nt] = bias[F0 + nt * 16 + m];

  if (which == 2) {
    // ---- V epilogue via LDS transpose: one head per pass ----
    _Float16* Vl = smem;               // [64 d][132] halfs = 16896 B
    const int bb = m0 >> 11, n0 = m0 & 2047;
    const int head_base = (N0 & 1023) >> 6;
#pragma unroll
    for (int hl = 0; hl < 2; ++hl) {
      __syncthreads();                 // LDS free (main loop / prev pass done)
      if ((w & 1) == hl) {
#pragma unroll
        for (int mt = 0; mt < 4; ++mt)
#pragma unroll
          for (int nt = 0; nt < 4; ++nt) {
            half4_t h4;
#pragma unroll
            for (int reg = 0; reg < 4; ++reg)
              h4[reg] = (_Float16)(acc[mt][nt][reg] + bv[nt]);
            *(half4_t*)(Vl + (nt * 16 + m) * 132 + wr + mt * 16 + 4 * quad) = h4;
          }
      }
      __syncthreads();
      const size_t vrow = (size_t)(bb * NH + head_base + hl) * DH;
#pragma unroll
      for (int p = 0; p < 4; ++p) {
        const int idx = p * 256 + tid;       // 0..1023
        const int d = idx >> 4, ch = idx & 15;
        half8_t v = *(half8_t*)(Vl + d * 132 + ch * 8);
        *(half8_t*)(Vh + (vrow + d) * NSEQ + n0 + ch * 8) = v;
      }
    }
  } else {
    _Float16* dst = which ? Kh : Qh;
    const float qs = which ? 1.0f : 0.125f * 1.4426950408889634f;
    float ssum[4][4];
#pragma unroll
    for (int mt = 0; mt < 4; ++mt)
#pragma unroll
      for (int reg = 0; reg < 4; ++reg) ssum[mt][reg] = 0.f;
#pragma unroll
    for (int mt = 0; mt < 4; ++mt)
#pragma unroll
      for (int reg = 0; reg < 4; ++reg) {
        const int gm = m0 + wr + mt * 16 + 4 * quad + reg;
        const int b = gm >> 11, n = gm & 2047;
        const float2 csA = rope[n * 32 + m];       // freq index m
        const float2 csB = rope[n * 32 + 16 + m];  // freq index 16+m
        const size_t obase = ((size_t)(b * NH + head) * NSEQ + n) * DH;
#pragma unroll
        for (int nt = 0; nt < 4; ++nt) {
          const float val = acc[mt][nt][reg] + bv[nt];
          const float rot = (nt < 2) ? -(acc[mt][nt + 2][reg] + bv[nt + 2])
                                     :  (acc[mt][nt - 2][reg] + bv[nt - 2]);
          const float sv = (nt & 1) ? csB.y : csA.y;
          const float cv = (nt & 1) ? csB.x : csA.x;
          const _Float16 h16 = (_Float16)((val * cv + rot * sv) * qs);
          dst[obase + nt * 16 + m] = h16;
          const float vv = (float)h16;
          ssum[mt][reg] += vv * vv;
        }
      }
    // row sums: reduce over the 16 m-lanes (dims nt*16+m; nt already summed)
#pragma unroll
    for (int mt = 0; mt < 4; ++mt)
#pragma unroll
      for (int reg = 0; reg < 4; ++reg) {
        float s = ssum[mt][reg];
        s += __shfl_xor(s, 1, 64);
        s += __shfl_xor(s, 2, 64);
        s += __shfl_xor(s, 4, 64);
        s += __shfl_xor(s, 8, 64);
        ssum[mt][reg] = s;
      }
    if (which == 0) {
      if (m == 0) {
#pragma unroll
        for (int mt = 0; mt < 4; ++mt)
#pragma unroll
          for (int reg = 0; reg < 4; ++reg) {
            const int gm = m0 + wr + mt * 16 + 4 * quad + reg;
            const int b = gm >> 11, n = gm & 2047;
            qn[(size_t)(b * NH + head) * NSEQ + n] = sqrtf(ssum[mt][reg]);
          }
      }
    } else {
      float mx = 0.f;
#pragma unroll
      for (int mt = 0; mt < 4; ++mt)
#pragma unroll
        for (int reg = 0; reg < 4; ++reg) mx = fmaxf(mx, ssum[mt][reg]);
      mx = fmaxf(mx, __shfl_xor(mx, 16, 64));
      mx = fmaxf(mx, __shfl_xor(mx, 32, 64));
      if (lane == 0) {
        const int b = m0 >> 11;   // 128-row block never straddles a batch
        atomicMax(&kmaxu[(b * NH + head) * KMAX_STRIDE],
                  __float_as_uint(sqrtf(mx)));
      }
    }
  }
}

// ---------------------------------------------------------------------------
// Kernel 2: flash attention (R10 structure, unchanged: 512 thr / 8 waves,
// 16 q-rows per wave, VGPR<=64 -> 8 waves/SIMD, XCD-aware decode).
// ---------------------------------------------------------------------------
__global__ __launch_bounds__(512, 8) void attn_kernel(
    const _Float16* __restrict__ Qh, const _Float16* __restrict__ Kh,
    const _Float16* __restrict__ Vh, const float* __restrict__ qn,
    const unsigned* __restrict__ kmaxu, _Float16* __restrict__ AO) {
  __shared__ _Float16 smem[17408];   // 34816 B: Ks[64][72]+Vt[64][72] stage
  float* Os = (float*)smem;          // epilogue reuse: float[128][68]
  _Float16* Ks = smem;               // [64][72]
  _Float16* Vt = smem + 4608;        // [64][72]

  const int tid = threadIdx.x;
  const int lane = tid & 63;
  const int w = tid >> 6;            // 0..7
  const int m = lane & 15;
  const int quad = lane >> 4;

  // XCD-aware decode: slot = id%8 (XCD), k = id/8; bh = slot + 8*(k/16)
  const int bid = blockIdx.x;
  const int slot = bid & 7, kk = bid >> 3;
  const int bh = slot + 8 * (kk >> 4);
  const int q0 = (kk & 15) * 128;

  const _Float16* Qb = Qh + (size_t)bh * NSEQ * DH;
  const _Float16* Kb = Kh + (size_t)bh * NSEQ * DH;
  const _Float16* Vb = Vh + (size_t)bh * DH * NSEQ;

  const int rA = q0 + w * 16 + m;    // wave w owns rows q0+w*16 .. +16
  half8_t qfA0 = *(const half8_t*)(Qb + (size_t)rA * DH + quad * 8);
  half8_t qfA1 = *(const half8_t*)(Qb + (size_t)rA * DH + 32 + quad * 8);

  const float kmx = __uint_as_float(kmaxu[bh * KMAX_STRIDE]);
  const float mA = qn[(size_t)bh * NSEQ + rA] * kmx;

  // staging: 512 threads, each moves 1 K half8 + 1 V half8 per chunk
  const int skey = tid >> 3, sdg = (tid & 7) * 8;
  const _Float16* ksrc = Kb + (size_t)skey * DH + sdg;
  const _Float16* vsrc = Vb + (size_t)skey * NSEQ + sdg;
  const int koff = skey * 72 + sdg;

  float lA = 0.f;
  floatx4 OA[4];
#pragma unroll
  for (int nb = 0; nb < 4; ++nb) OA[nb] = (floatx4){0.f, 0.f, 0.f, 0.f};
  const pk2_t one2 = {(__fp16)1.f, (__fp16)1.f};

  const int NCK = NSEQ / KC;  // 32
  for (int ck = 0; ck < NCK; ++ck) {
    half8_t k8 = *(const half8_t*)ksrc;  ksrc += KC * DH;
    half8_t v8 = *(const half8_t*)vsrc;  vsrc += KC;
    __syncthreads();                 // prev compute done, LDS free
    *(half8_t*)(Ks + koff) = k8;
    *(half8_t*)(Vt + koff) = v8;
    __syncthreads();                 // stage visible

#pragma unroll
    for (int kt = 0; kt < 4; ++kt) {
      half8_t kf0 = *(half8_t*)(Ks + (kt * 16 + m) * 72 + quad * 8);
      half8_t kf1 = *(half8_t*)(Ks + (kt * 16 + m) * 72 + 32 + quad * 8);
      __builtin_amdgcn_s_setprio(1);
      floatx4 a = (floatx4){-mA, -mA, -mA, -mA};
      a = __builtin_amdgcn_mfma_f32_16x16x32_f16(kf0, qfA0, a, 0, 0, 0);
      a = __builtin_amdgcn_mfma_f32_16x16x32_f16(kf1, qfA1, a, 0, 0, 0);
      __builtin_amdgcn_s_setprio(0);

      pk2_t a01 = __builtin_amdgcn_cvt_pkrtz(__builtin_exp2f(a[0]),
                                             __builtin_exp2f(a[1]));
      pk2_t a23 = __builtin_amdgcn_cvt_pkrtz(__builtin_exp2f(a[2]),
                                             __builtin_exp2f(a[3]));
      lA = __builtin_amdgcn_fdot2(a01, one2, lA, false);
      lA = __builtin_amdgcn_fdot2(a23, one2, lA, false);
      half4_t phA = __builtin_bit_cast(
          half4_t, (pk4_t)__builtin_shufflevector(a01, a23, 0, 1, 2, 3));

      __builtin_amdgcn_s_setprio(1);
#pragma unroll
      for (int nb = 0; nb < 4; ++nb) {
        half4_t vf = *(half4_t*)(Vt + (nb * 16 + m) * 72 + kt * 16 + quad * 4);
        OA[nb] = __builtin_amdgcn_mfma_f32_16x16x16f16(phA, vf, OA[nb], 0, 0, 0);
      }
      __builtin_amdgcn_s_setprio(0);
    }
  }

  // row-sum across quads (lanes differing in bits 4,5)
  lA += __shfl_xor(lA, 16, 64); lA += __shfl_xor(lA, 32, 64);
  float lA4[4];
#pragma unroll
  for (int r = 0; r < 4; ++r) lA4[r] = __shfl(lA, 4 * quad + r, 64);

  const int b = bh >> 4, h = bh & 15;
  const int ql = tid >> 2, dgo = (tid & 3) * 16;   // ql 0..127
  const int gq = q0 + ql;
  _Float16* dst = AO + ((size_t)(b * NSEQ + gq)) * CDIM + h * DH + dgo;

  __syncthreads();   // all compute reads of Ks/Vt done before Os overwrite
#pragma unroll
  for (int nb = 0; nb < 4; ++nb)
#pragma unroll
    for (int r = 0; r < 4; ++r)
      Os[(w * 16 + 4 * quad + r) * 68 + nb * 16 + m] = OA[nb][r] * (1.0f / lA4[r]);
  __syncthreads();
#pragma unroll
  for (int u = 0; u < 2; ++u) {
    half8_t o;
#pragma unroll
    for (int v = 0; v < 8; ++v) o[v] = (_Float16)Os[ql * 68 + dgo + u * 8 + v];
    *(half8_t*)(dst + u * 8) = o;
  }
}

// ---------------------------------------------------------------------------
// Kernel 3: proj GEMM (fp16 MFMA) + bias, fp32 out (unchanged R3).
// ---------------------------------------------------------------------------
__global__ __launch_bounds__(256) void proj_gemm_kernel(
    const _Float16* __restrict__ Ah, const _Float16* __restrict__ Wt,
    const float* __restrict__ bias, float* __restrict__ out) {
  __shared__ _Float16 As[128 * 64];
  __shared__ _Float16 Bs[128 * 64];
  const int tid = threadIdx.x;
  const int lane = tid & 63, w = tid >> 6;
  const int m = lane & 15, quad = lane >> 4;
  const int wr = (w >> 1) * 64, wc = (w & 1) * 64;
  const int m0 = blockIdx.y * 128;
  const int N0 = blockIdx.x * 128;
  const int sr = lane >> 3, sc = (lane & 7) * 8;

  floatx4 acc[4][4];
#pragma unroll
  for (int i = 0; i < 4; ++i)
#pragma unroll
    for (int j = 0; j < 4; ++j) acc[i][j] = (floatx4){0.f, 0.f, 0.f, 0.f};

  for (int k0 = 0; k0 < CDIM; k0 += 64) {
    __syncthreads();
#pragma unroll
    for (int i = 0; i < 4; ++i) {
      const int row = (w * 4 + i) * 8 + sr;
      __builtin_amdgcn_global_load_lds(
          GLOBAL_AS(Ah + (size_t)(m0 + row) * CDIM + k0 + sc),
          LDS_AS(As + (w * 4 + i) * 512), 16, 0, 0);
      __builtin_amdgcn_global_load_lds(
          GLOBAL_AS(Wt + (size_t)(N0 + row) * CDIM + k0 + sc),
          LDS_AS(Bs + (w * 4 + i) * 512), 16, 0, 0);
    }
    __syncthreads();
#pragma unroll
    for (int ks = 0; ks < 2; ++ks) {
      half8_t af[4], bf[4];
#pragma unroll
      for (int mt = 0; mt < 4; ++mt)
        af[mt] = *(half8_t*)(As + (wr + mt * 16 + m) * 64 + ks * 32 + quad * 8);
#pragma unroll
      for (int nt = 0; nt < 4; ++nt)
        bf[nt] = *(half8_t*)(Bs + (wc + nt * 16 + m) * 64 + ks * 32 + quad * 8);
#pragma unroll
      for (int mt = 0; mt < 4; ++mt)
#pragma unroll
        for (int nt = 0; nt < 4; ++nt)
          acc[mt][nt] = __builtin_amdgcn_mfma_f32_16x16x32_f16(
              af[mt], bf[nt], acc[mt][nt], 0, 0, 0);
    }
  }

  const int F0 = N0 + wc;
  float bv[4];
#pragma unroll
  for (int nt = 0; nt < 4; ++nt) bv[nt] = bias[F0 + nt * 16 + m];
#pragma unroll
  for (int mt = 0; mt < 4; ++mt)
#pragma unroll
    for (int reg = 0; reg < 4; ++reg) {
      const int gm = m0 + wr + mt * 16 + 4 * quad + reg;
#pragma unroll
      for (int nt = 0; nt < 4; ++nt)
        out[(size_t)gm * CDIM + F0 + nt * 16 + m] = acc[mt][nt][reg] + bv[nt];
    }
}

// ---------------------------------------------------------------------------
extern "C" void kernel_launch(void* const* d_in, const int* in_sizes, int n_in,
                              void* d_out, int out_size, void* d_ws, size_t ws_size,
                              hipStream_t stream) {
  const float* x     = (const float*)d_in[0];
  const float* Wqkv  = (const float*)d_in[1];
  const float* bqkv  = (const float*)d_in[2];
  const float* Wproj = (const float*)d_in[3];
  const float* bproj = (const float*)d_in[4];
  float* out = (float*)d_out;

  const size_t per = (size_t)BSZ * NH * NSEQ * DH;  // 8,388,608
  _Float16* xh  = (_Float16*)d_ws;
  _Float16* Wt  = xh + per;                 // [3072][1024]
  _Float16* Wpt = Wt + (size_t)3072 * 1024; // [1024][1024]
  _Float16* Qh  = Wpt + (size_t)1024 * 1024;
  _Float16* Kh  = Qh + per;
  _Float16* Vh  = Kh + per;
  _Float16* AOh = Vh + per;
  float*    qnp = (float*)(AOh + per);      // [64*2048] q-row norms
  unsigned* kmx = (unsigned*)(qnp + (size_t)64 * NSEQ);  // [64*KMAX_STRIDE]
  float2*   ropet = (float2*)(kmx + 64 * KMAX_STRIDE);   // [2048*32] (cos,sin)

  prep_kernel<<<5376, 256, 0, stream>>>(x, Wqkv, Wproj, xh, Wt, Wpt, ropet, kmx);
  qkv_gemm_kernel<<<dim3(24, 64), 256, 0, stream>>>(xh, Wt, bqkv, ropet,
                                                    Qh, Kh, Vh, qnp, kmx);
  attn_kernel<<<1024, 512, 0, stream>>>(Qh, Kh, Vh, qnp, kmx, AOh);
  proj_gemm_kernel<<<dim3(8, 64), 256, 0, stream>>>(AOh, Wpt, bproj, out);
}